// Round 4
// baseline (740.643 us; speedup 1.0000x reference)
//
#include <hip/hip_runtime.h>
#include <stdint.h>

typedef unsigned short u16;
typedef __attribute__((ext_vector_type(8))) short short8;
typedef __attribute__((ext_vector_type(4))) float floatx4;

#define MFMA16(a, b, c) __builtin_amdgcn_mfma_f32_16x16x32_bf16(a, b, c, 0, 0, 0)

static __device__ __forceinline__ void gl_lds16(const void* g, void* l) {
  __builtin_amdgcn_global_load_lds(
      (const __attribute__((address_space(1))) uint32_t*)g,
      (__attribute__((address_space(3))) uint32_t*)l, 16, 0, 0);
}

static __device__ __forceinline__ float b2f(u16 u) {
  union { float f; unsigned u; } v;
  v.u = ((unsigned)u) << 16;
  return v.f;
}
static __device__ __forceinline__ u16 f2b(float f) {
  union { float f; unsigned u; } v;
  v.f = f;
  unsigned r = v.u + 0x7fffu + ((v.u >> 16) & 1u);  // RNE
  return (u16)(r >> 16);
}

// DPP row-rotate reductions over 16-lane groups (VALU, no LDS traffic).
template <int CTRL>
static __device__ __forceinline__ float dppf(float x) {
  return __builtin_bit_cast(
      float, __builtin_amdgcn_update_dpp(0, __builtin_bit_cast(int, x), CTRL,
                                         0xF, 0xF, true));
}
static __device__ __forceinline__ float sum16(float x) {
  x += dppf<0x128>(x);  // row_ror:8
  x += dppf<0x124>(x);  // row_ror:4
  x += dppf<0x122>(x);  // row_ror:2
  x += dppf<0x121>(x);  // row_ror:1
  return x;
}
static __device__ __forceinline__ float max16(float x) {
  x = fmaxf(x, dppf<0x128>(x));
  x = fmaxf(x, dppf<0x124>(x));
  x = fmaxf(x, dppf<0x122>(x));
  x = fmaxf(x, dppf<0x121>(x));
  return x;
}

// ---------------------------------------------------------------------------
// Input-dtype detector (f32 vs bf16), proven round 2.
// ---------------------------------------------------------------------------
__global__ __launch_bounds__(256) void detect_f32(const u16* __restrict__ x,
                                                  int* __restrict__ flag) {
  __shared__ int cnt[256];
  int c = 0;
  for (int i = threadIdx.x; i < 65536; i += 256) {
    int e = (x[i] >> 7) & 0xFF;
    if (e >= 140) ++c;
  }
  cnt[threadIdx.x] = c;
  __syncthreads();
  for (int s = 128; s > 0; s >>= 1) {
    if (threadIdx.x < (unsigned)s) cnt[threadIdx.x] += cnt[threadIdx.x + s];
    __syncthreads();
  }
  if (threadIdx.x == 0) *flag = (cnt[0] > 1000) ? 1 : 0;
}

__global__ __launch_bounds__(256) void convert_in(const void* __restrict__ src,
                                                  u16* __restrict__ dst, int n,
                                                  const int* __restrict__ flag) {
  int i = blockIdx.x * 256 + threadIdx.x;
  if (i >= n) return;
  if (*flag)
    dst[i] = f2b(((const float*)src)[i]);
  else
    dst[i] = ((const u16*)src)[i];
}

__global__ __launch_bounds__(256) void transpose_conv(const void* __restrict__ in,
                                                      u16* __restrict__ out,
                                                      int R, int Ccols,
                                                      const int* __restrict__ flag) {
  __shared__ u16 tile[32][33];
  int f = *flag;
  int c0 = blockIdx.x * 32, r0 = blockIdx.y * 32;
  int lx = threadIdx.x & 31, ly = threadIdx.x >> 5;
#pragma unroll
  for (int i = 0; i < 32; i += 8) {
    size_t idx = (size_t)(r0 + ly + i) * Ccols + c0 + lx;
    tile[ly + i][lx] = f ? f2b(((const float*)in)[idx]) : ((const u16*)in)[idx];
  }
  __syncthreads();
#pragma unroll
  for (int i = 0; i < 32; i += 8)
    out[(size_t)(c0 + ly + i) * R + r0 + lx] = tile[lx][ly + i];
}

// V half of KV [4096][4096] -> Vt[b][d][s]  ([2][2048][2048])
__global__ __launch_bounds__(256) void transpose_v(const u16* __restrict__ KV,
                                                   u16* __restrict__ Vt) {
  __shared__ u16 tile[32][33];
  int b = blockIdx.z;
  int d0 = blockIdx.x * 32, s0 = blockIdx.y * 32;
  int lx = threadIdx.x & 31, ly = threadIdx.x >> 5;
  const u16* src = KV + ((size_t)(b * 2048 + s0)) * 4096 + 2048 + d0;
#pragma unroll
  for (int i = 0; i < 32; i += 8)
    tile[ly + i][lx] = src[(size_t)(ly + i) * 4096 + lx];  // tile[s][d]
  __syncthreads();
  u16* dst = Vt + ((size_t)(b * 2048 + d0)) * 2048 + s0;
#pragma unroll
  for (int i = 0; i < 32; i += 8)
    dst[(size_t)(ly + i) * 2048 + lx] = tile[lx][ly + i];  // Vt[d][s]
}

// ---------------------------------------------------------------------------
// NT GEMM (m97 structure) — unchanged (passed rounds 2-3).
// ---------------------------------------------------------------------------
__global__ __launch_bounds__(256) void gemm_nt(const u16* __restrict__ A,
                                               const u16* __restrict__ Bm,
                                               void* __restrict__ Cv,
                                               int M, int N, int K,
                                               const int* __restrict__ flag,
                                               int flag_mode) {
  __shared__ u16 Ash[128 * 64];
  __shared__ u16 Bsh[128 * 64];
  int tid = threadIdx.x, w = tid >> 6, lane = tid & 63;
  int quad = lane >> 4, l15 = lane & 15;
  int m0 = blockIdx.y * 128, n0 = blockIdx.x * 128;
  int wm = (w & 1) * 64, wn = (w >> 1) * 64;
  int f32out = flag_mode ? *flag : 0;

  floatx4 acc[4][4];
#pragma unroll
  for (int i = 0; i < 4; ++i)
#pragma unroll
    for (int j = 0; j < 4; ++j) acc[i][j] = floatx4{0.f, 0.f, 0.f, 0.f};

  int srow = lane >> 3;
  int gch = (lane & 7) ^ srow;
  const u16* Ag = A + (size_t)(m0 + w * 32 + srow) * K + gch * 8;
  const u16* Bg = Bm + (size_t)(n0 + w * 32 + srow) * K + gch * 8;

  for (int k0 = 0; k0 < K; k0 += 64) {
    __syncthreads();
#pragma unroll
    for (int t = 0; t < 4; ++t) {
      gl_lds16(Ag + (size_t)t * 8 * K + k0, (void*)(Ash + (w * 32 + t * 8) * 64));
      gl_lds16(Bg + (size_t)t * 8 * K + k0, (void*)(Bsh + (w * 32 + t * 8) * 64));
    }
    __syncthreads();
#pragma unroll
    for (int kk = 0; kk < 2; ++kk) {
      int c = kk * 4 + quad;
      short8 af[4], bf[4];
#pragma unroll
      for (int i = 0; i < 4; ++i) {
        int m = wm + 16 * i + l15;
        af[i] = *(const short8*)(Ash + m * 64 + ((c ^ (m & 7)) << 3));
        int n = wn + 16 * i + l15;
        bf[i] = *(const short8*)(Bsh + n * 64 + ((c ^ (n & 7)) << 3));
      }
#pragma unroll
      for (int i = 0; i < 4; ++i)
#pragma unroll
        for (int j = 0; j < 4; ++j) acc[i][j] = MFMA16(af[i], bf[j], acc[i][j]);
    }
  }

#pragma unroll
  for (int i = 0; i < 4; ++i)
#pragma unroll
    for (int r = 0; r < 4; ++r) {
      int row = m0 + wm + 16 * i + quad * 4 + r;
      if (f32out) {
        float* cp = (float*)Cv + (size_t)row * N + n0 + wn + l15;
#pragma unroll
        for (int j = 0; j < 4; ++j) cp[16 * j] = acc[i][j][r];
      } else {
        u16* cp = (u16*)Cv + (size_t)row * N + n0 + wn + l15;
#pragma unroll
        for (int j = 0; j < 4; ++j) cp[16 * j] = f2b(acc[i][j][r]);
      }
    }
}

// ---------------------------------------------------------------------------
// RoPE in-place; Q additionally scaled by 1/sqrt(dh) (folded from attention).
// ---------------------------------------------------------------------------
__global__ __launch_bounds__(256) void rope_kernel(u16* __restrict__ Q,
                                                   u16* __restrict__ KV) {
  const float scale = 0.08838834764831845f;  // 1/sqrt(128)
  int idx = blockIdx.x * 256 + threadIdx.x;
  int tok = idx >> 10;
  int rem = idx & 1023;
  int h = rem >> 6, i = rem & 63;
  int pos = tok & 2047;
  float f = __powf(10000.0f, -(float)(2 * i) * (1.0f / 128.0f));
  float ang = (float)pos * f;
  float s, c;
  sincosf(ang, &s, &c);

  size_t qb = (size_t)tok * 2048 + h * 128 + i;
  float q1 = b2f(Q[qb]), q2 = b2f(Q[qb + 64]);
  Q[qb] = f2b((q1 * c - q2 * s) * scale);
  Q[qb + 64] = f2b((q2 * c + q1 * s) * scale);

  size_t kb = (size_t)tok * 4096 + h * 128 + i;
  float k1 = b2f(KV[kb]), k2 = b2f(KV[kb + 64]);
  KV[kb] = f2b(k1 * c - k2 * s);
  KV[kb + 64] = f2b(k2 * c + k1 * s);
}

// ---------------------------------------------------------------------------
// Flash attention v3. Block = (bh, qt); 512 blocks, big-qt dispatched first,
// 3 blocks/CU co-resident (LDS 48KB, VGPR cap 170 via launch_bounds(256,3)).
// Q-tile 128 rows (wave = 32 rows), k-tile 64; staging via global_load_lds
// with XOR-swizzled global chunks; all LDS reads ds_read_b128, <=2-way banks.
// ---------------------------------------------------------------------------
__global__ __launch_bounds__(256, 3) void flash_attn(const u16* __restrict__ Q,
                                                     const u16* __restrict__ KV,
                                                     const u16* __restrict__ Vt,
                                                     u16* __restrict__ O) {
  const int S = 2048, D = 2048, KVld = 4096;
  int bh = blockIdx.x;          // 0..31
  int qt = 15 - blockIdx.y;     // 15..0 — long blocks launch first
  int b = bh >> 4, h = bh & 15;
  int tid = threadIdx.x, w = tid >> 6, lane = tid & 63;
  int quad = lane >> 4, l15 = lane & 15;

  const u16* Qb = Q + (size_t)(b * S) * D + h * 128;
  const u16* Kb = KV + (size_t)(b * S) * KVld + h * 128;
  const u16* Vtb = Vt + ((size_t)(b * 2048 + h * 128)) * S;

  __shared__ u16 Ksh[64 * 128];
  __shared__ u16 Vsh[128 * 64];
  __shared__ u16 Psh[4][32 * 64];

  int q0 = qt * 128;
  int qw = q0 + w * 32;

  short8 qf[2][4];
#pragma unroll
  for (int mi = 0; mi < 2; ++mi) {
    const u16* qp = Qb + (size_t)(qw + mi * 16 + l15) * D + quad * 8;
#pragma unroll
    for (int kk = 0; kk < 4; ++kk) qf[mi][kk] = *(const short8*)(qp + kk * 32);
  }

  floatx4 o[2][8];
#pragma unroll
  for (int mi = 0; mi < 2; ++mi)
#pragma unroll
    for (int t = 0; t < 8; ++t) o[mi][t] = floatx4{0.f, 0.f, 0.f, 0.f};
  float mrow[2][4], lrow[2][4];
#pragma unroll
  for (int mi = 0; mi < 2; ++mi)
#pragma unroll
    for (int r = 0; r < 4; ++r) { mrow[mi][r] = -1e30f; lrow[mi][r] = 0.f; }

  int nk = 2 * qt + 2;
  for (int kt = 0; kt < nk; ++kt) {
    int kb = kt * 64;
    __syncthreads();

    // stage K tile [64][128]
#pragma unroll
    for (int tt = 0; tt < 4; ++tt) {
      int r0 = w * 16 + tt * 4;
      int row = r0 + quad;
      int g = (l15 & 8) | ((l15 & 7) ^ (row & 7));
      gl_lds16(Kb + (size_t)(kb + row) * KVld + g * 8, (void*)(Ksh + r0 * 128));
    }
    // stage V^T tile [128][64]
#pragma unroll
    for (int tt = 0; tt < 4; ++tt) {
      int d0 = w * 32 + tt * 8;
      int d = d0 + (lane >> 3);
      int g = (lane & 7) ^ (d & 7);
      gl_lds16(Vtb + (size_t)d * S + kb + g * 8, (void*)(Vsh + d0 * 64));
    }
    __syncthreads();

    if (kb <= qw + 31) {
      // --- QK^T: 2m x 4n x 4ksteps = 32 MFMA ---
      floatx4 sc[2][4];
#pragma unroll
      for (int mi = 0; mi < 2; ++mi)
#pragma unroll
        for (int nf = 0; nf < 4; ++nf) sc[mi][nf] = floatx4{0.f, 0.f, 0.f, 0.f};
#pragma unroll
      for (int kk = 0; kk < 4; ++kk) {
        short8 kf[4];
        int c = kk * 4 + quad;
#pragma unroll
        for (int nf = 0; nf < 4; ++nf) {
          int n = nf * 16 + l15;
          int pc = (c & 8) | ((c & 7) ^ (n & 7));
          kf[nf] = *(const short8*)(Ksh + n * 128 + pc * 8);
        }
#pragma unroll
        for (int mi = 0; mi < 2; ++mi)
#pragma unroll
          for (int nf = 0; nf < 4; ++nf)
            sc[mi][nf] = MFMA16(qf[mi][kk], kf[nf], sc[mi][nf]);
      }

      // --- online softmax (scale pre-folded into Q) ---
      bool masked = (kb + 63 > qw);
#pragma unroll
      for (int mi = 0; mi < 2; ++mi) {
        floatx4 alv;
#pragma unroll
        for (int r = 0; r < 4; ++r) {
          int qg = qw + mi * 16 + quad * 4 + r;
          float v0 = sc[mi][0][r], v1 = sc[mi][1][r];
          float v2 = sc[mi][2][r], v3 = sc[mi][3][r];
          if (masked) {
            v0 = (kb + l15 <= qg) ? v0 : -1e30f;
            v1 = (kb + 16 + l15 <= qg) ? v1 : -1e30f;
            v2 = (kb + 32 + l15 <= qg) ? v2 : -1e30f;
            v3 = (kb + 48 + l15 <= qg) ? v3 : -1e30f;
          }
          float mx = max16(fmaxf(fmaxf(v0, v1), fmaxf(v2, v3)));
          float mn = fmaxf(mrow[mi][r], mx);
          float al = __expf(mrow[mi][r] - mn);
          mrow[mi][r] = mn;
          float p0 = __expf(v0 - mn), p1 = __expf(v1 - mn);
          float p2 = __expf(v2 - mn), p3 = __expf(v3 - mn);
          float rs = sum16((p0 + p1) + (p2 + p3));
          lrow[mi][r] = lrow[mi][r] * al + rs;
          alv[r] = al;
          int m_ = mi * 16 + quad * 4 + r, sw = m_ & 7;
          int cb = l15 >> 3, e = l15 & 7;
          u16* pr = Psh[w] + m_ * 64;
          pr[(((0 + cb) ^ sw) << 3) + e] = f2b(p0);
          pr[(((2 + cb) ^ sw) << 3) + e] = f2b(p1);
          pr[(((4 + cb) ^ sw) << 3) + e] = f2b(p2);
          pr[(((6 + cb) ^ sw) << 3) + e] = f2b(p3);
        }
#pragma unroll
        for (int t = 0; t < 8; ++t) o[mi][t] *= alv;  // v_pk_mul_f32-able
      }
      __asm__ volatile("s_waitcnt lgkmcnt(0)" ::: "memory");

      // --- PV: 2m x 8d x 2ksteps = 32 MFMA ---
#pragma unroll
      for (int ks = 0; ks < 2; ++ks) {
        int c = ks * 4 + quad;
        short8 pf[2];
#pragma unroll
        for (int mi = 0; mi < 2; ++mi) {
          int m_ = mi * 16 + l15;
          pf[mi] = *(const short8*)(Psh[w] + m_ * 64 + ((c ^ (m_ & 7)) << 3));
        }
#pragma unroll
        for (int t = 0; t < 8; ++t) {
          int d = t * 16 + l15;
          short8 vf = *(const short8*)(Vsh + d * 64 + ((c ^ (d & 7)) << 3));
#pragma unroll
          for (int mi = 0; mi < 2; ++mi) o[mi][t] = MFMA16(pf[mi], vf, o[mi][t]);
        }
      }
    }
  }

  // epilogue
#pragma unroll
  for (int mi = 0; mi < 2; ++mi)
#pragma unroll
    for (int r = 0; r < 4; ++r) {
      float inv = 1.0f / lrow[mi][r];
      int qg = qw + mi * 16 + quad * 4 + r;
      u16* op = O + (size_t)(b * S + qg) * D + h * 128;
#pragma unroll
      for (int t = 0; t < 8; ++t) op[t * 16 + l15] = f2b(o[mi][t][r] * inv);
    }
}

// ---------------------------------------------------------------------------
// Launch. ws (u16 after 64-elem flag pad):
//   xb 8.4M | Wbuf 8.4M (wq -> wkvT -> Vt -> wo) | Qb 8.4M | KVb 16.8M
//   AO aliases xb. Total ~84 MB.
// ---------------------------------------------------------------------------
extern "C" void kernel_launch(void* const* d_in, const int* in_sizes, int n_in,
                              void* d_out, int out_size, void* d_ws, size_t ws_size,
                              hipStream_t stream) {
  const void* x = d_in[0];
  const void* wq = d_in[1];
  const void* wkv = d_in[2];
  const void* wo = d_in[3];

  int* flag = (int*)d_ws;
  u16* xb = (u16*)d_ws + 64;
  u16* Wbuf = xb + (size_t)8388608;
  u16* Qb = Wbuf + (size_t)8388608;
  u16* KVb = Qb + (size_t)8388608;
  u16* AO = xb;  // x dead after KV projection

  detect_f32<<<1, 256, 0, stream>>>((const u16*)x, flag);
  convert_in<<<32768, 256, 0, stream>>>(x, xb, 8388608, flag);
  convert_in<<<16384, 256, 0, stream>>>(wq, Wbuf, 4194304, flag);
  gemm_nt<<<dim3(16, 32), 256, 0, stream>>>(xb, Wbuf, Qb, 4096, 2048, 2048, flag, 0);
  transpose_conv<<<dim3(128, 64), 256, 0, stream>>>(wkv, Wbuf, 2048, 4096, flag);
  gemm_nt<<<dim3(32, 32), 256, 0, stream>>>(xb, Wbuf, KVb, 4096, 4096, 2048, flag, 0);
  transpose_v<<<dim3(64, 64, 2), 256, 0, stream>>>(KVb, Wbuf);  // Wbuf := Vt
  rope_kernel<<<16384, 256, 0, stream>>>(Qb, KVb);
  flash_attn<<<dim3(32, 16), 256, 0, stream>>>(Qb, KVb, Wbuf, AO);
  convert_in<<<16384, 256, 0, stream>>>(wo, Wbuf, 4194304, flag);
  gemm_nt<<<dim3(16, 32), 256, 0, stream>>>(AO, Wbuf, d_out, 4096, 2048, 2048, flag, 1);
}

// Round 5
// 522.320 us; speedup vs baseline: 1.4180x; 1.4180x over previous
//
#include <hip/hip_runtime.h>
#include <stdint.h>

typedef unsigned short u16;
typedef __attribute__((ext_vector_type(8))) short short8;
typedef __attribute__((ext_vector_type(4))) float floatx4;

#define MFMA16(a, b, c) __builtin_amdgcn_mfma_f32_16x16x32_bf16(a, b, c, 0, 0, 0)

static __device__ __forceinline__ void gl_lds16(const void* g, void* l) {
  __builtin_amdgcn_global_load_lds(
      (const __attribute__((address_space(1))) uint32_t*)g,
      (__attribute__((address_space(3))) uint32_t*)l, 16, 0, 0);
}

static __device__ __forceinline__ float b2f(u16 u) {
  union { float f; unsigned u; } v;
  v.u = ((unsigned)u) << 16;
  return v.f;
}
static __device__ __forceinline__ u16 f2b(float f) {
  union { float f; unsigned u; } v;
  v.f = f;
  unsigned r = v.u + 0x7fffu + ((v.u >> 16) & 1u);  // RNE
  return (u16)(r >> 16);
}

// DPP row-rotate reductions over 16-lane groups (VALU, no LDS traffic).
template <int CTRL>
static __device__ __forceinline__ float dppf(float x) {
  return __builtin_bit_cast(
      float, __builtin_amdgcn_update_dpp(0, __builtin_bit_cast(int, x), CTRL,
                                         0xF, 0xF, true));
}
static __device__ __forceinline__ float sum16(float x) {
  x += dppf<0x128>(x);  // row_ror:8
  x += dppf<0x124>(x);  // row_ror:4
  x += dppf<0x122>(x);  // row_ror:2
  x += dppf<0x121>(x);  // row_ror:1
  return x;
}
static __device__ __forceinline__ float max16(float x) {
  x = fmaxf(x, dppf<0x128>(x));
  x = fmaxf(x, dppf<0x124>(x));
  x = fmaxf(x, dppf<0x122>(x));
  x = fmaxf(x, dppf<0x121>(x));
  return x;
}

// ---------------------------------------------------------------------------
// Input-dtype detector (f32 vs bf16), proven round 2.
// ---------------------------------------------------------------------------
__global__ __launch_bounds__(256) void detect_f32(const u16* __restrict__ x,
                                                  int* __restrict__ flag) {
  __shared__ int cnt[256];
  int c = 0;
  for (int i = threadIdx.x; i < 65536; i += 256) {
    int e = (x[i] >> 7) & 0xFF;
    if (e >= 140) ++c;
  }
  cnt[threadIdx.x] = c;
  __syncthreads();
  for (int s = 128; s > 0; s >>= 1) {
    if (threadIdx.x < (unsigned)s) cnt[threadIdx.x] += cnt[threadIdx.x + s];
    __syncthreads();
  }
  if (threadIdx.x == 0) *flag = (cnt[0] > 1000) ? 1 : 0;
}

__global__ __launch_bounds__(256) void convert_in(const void* __restrict__ src,
                                                  u16* __restrict__ dst, int n,
                                                  const int* __restrict__ flag) {
  int i = blockIdx.x * 256 + threadIdx.x;
  if (i >= n) return;
  if (*flag)
    dst[i] = f2b(((const float*)src)[i]);
  else
    dst[i] = ((const u16*)src)[i];
}

__global__ __launch_bounds__(256) void transpose_conv(const void* __restrict__ in,
                                                      u16* __restrict__ out,
                                                      int R, int Ccols,
                                                      const int* __restrict__ flag) {
  __shared__ u16 tile[32][33];
  int f = *flag;
  int c0 = blockIdx.x * 32, r0 = blockIdx.y * 32;
  int lx = threadIdx.x & 31, ly = threadIdx.x >> 5;
#pragma unroll
  for (int i = 0; i < 32; i += 8) {
    size_t idx = (size_t)(r0 + ly + i) * Ccols + c0 + lx;
    tile[ly + i][lx] = f ? f2b(((const float*)in)[idx]) : ((const u16*)in)[idx];
  }
  __syncthreads();
#pragma unroll
  for (int i = 0; i < 32; i += 8)
    out[(size_t)(c0 + ly + i) * R + r0 + lx] = tile[lx][ly + i];
}

// V half of KV [4096][4096] -> Vt[b][d][s]  ([2][2048][2048])
__global__ __launch_bounds__(256) void transpose_v(const u16* __restrict__ KV,
                                                   u16* __restrict__ Vt) {
  __shared__ u16 tile[32][33];
  int b = blockIdx.z;
  int d0 = blockIdx.x * 32, s0 = blockIdx.y * 32;
  int lx = threadIdx.x & 31, ly = threadIdx.x >> 5;
  const u16* src = KV + ((size_t)(b * 2048 + s0)) * 4096 + 2048 + d0;
#pragma unroll
  for (int i = 0; i < 32; i += 8)
    tile[ly + i][lx] = src[(size_t)(ly + i) * 4096 + lx];  // tile[s][d]
  __syncthreads();
  u16* dst = Vt + ((size_t)(b * 2048 + d0)) * 2048 + s0;
#pragma unroll
  for (int i = 0; i < 32; i += 8)
    dst[(size_t)(ly + i) * 2048 + lx] = tile[lx][ly + i];  // Vt[d][s]
}

// ---------------------------------------------------------------------------
// NT GEMM (m97 structure) — unchanged (passed rounds 2-4).
// ---------------------------------------------------------------------------
__global__ __launch_bounds__(256) void gemm_nt(const u16* __restrict__ A,
                                               const u16* __restrict__ Bm,
                                               void* __restrict__ Cv,
                                               int M, int N, int K,
                                               const int* __restrict__ flag,
                                               int flag_mode) {
  __shared__ u16 Ash[128 * 64];
  __shared__ u16 Bsh[128 * 64];
  int tid = threadIdx.x, w = tid >> 6, lane = tid & 63;
  int quad = lane >> 4, l15 = lane & 15;
  int m0 = blockIdx.y * 128, n0 = blockIdx.x * 128;
  int wm = (w & 1) * 64, wn = (w >> 1) * 64;
  int f32out = flag_mode ? *flag : 0;

  floatx4 acc[4][4];
#pragma unroll
  for (int i = 0; i < 4; ++i)
#pragma unroll
    for (int j = 0; j < 4; ++j) acc[i][j] = floatx4{0.f, 0.f, 0.f, 0.f};

  int srow = lane >> 3;
  int gch = (lane & 7) ^ srow;
  const u16* Ag = A + (size_t)(m0 + w * 32 + srow) * K + gch * 8;
  const u16* Bg = Bm + (size_t)(n0 + w * 32 + srow) * K + gch * 8;

  for (int k0 = 0; k0 < K; k0 += 64) {
    __syncthreads();
#pragma unroll
    for (int t = 0; t < 4; ++t) {
      gl_lds16(Ag + (size_t)t * 8 * K + k0, (void*)(Ash + (w * 32 + t * 8) * 64));
      gl_lds16(Bg + (size_t)t * 8 * K + k0, (void*)(Bsh + (w * 32 + t * 8) * 64));
    }
    __syncthreads();
#pragma unroll
    for (int kk = 0; kk < 2; ++kk) {
      int c = kk * 4 + quad;
      short8 af[4], bf[4];
#pragma unroll
      for (int i = 0; i < 4; ++i) {
        int m = wm + 16 * i + l15;
        af[i] = *(const short8*)(Ash + m * 64 + ((c ^ (m & 7)) << 3));
        int n = wn + 16 * i + l15;
        bf[i] = *(const short8*)(Bsh + n * 64 + ((c ^ (n & 7)) << 3));
      }
#pragma unroll
      for (int i = 0; i < 4; ++i)
#pragma unroll
        for (int j = 0; j < 4; ++j) acc[i][j] = MFMA16(af[i], bf[j], acc[i][j]);
    }
  }

#pragma unroll
  for (int i = 0; i < 4; ++i)
#pragma unroll
    for (int r = 0; r < 4; ++r) {
      int row = m0 + wm + 16 * i + quad * 4 + r;
      if (f32out) {
        float* cp = (float*)Cv + (size_t)row * N + n0 + wn + l15;
#pragma unroll
        for (int j = 0; j < 4; ++j) cp[16 * j] = acc[i][j][r];
      } else {
        u16* cp = (u16*)Cv + (size_t)row * N + n0 + wn + l15;
#pragma unroll
        for (int j = 0; j < 4; ++j) cp[16 * j] = f2b(acc[i][j][r]);
      }
    }
}

// ---------------------------------------------------------------------------
// RoPE in-place; Q additionally scaled by 1/sqrt(dh) (folded from attention).
// ---------------------------------------------------------------------------
__global__ __launch_bounds__(256) void rope_kernel(u16* __restrict__ Q,
                                                   u16* __restrict__ KV) {
  const float scale = 0.08838834764831845f;  // 1/sqrt(128)
  int idx = blockIdx.x * 256 + threadIdx.x;
  int tok = idx >> 10;
  int rem = idx & 1023;
  int h = rem >> 6, i = rem & 63;
  int pos = tok & 2047;
  float f = __powf(10000.0f, -(float)(2 * i) * (1.0f / 128.0f));
  float ang = (float)pos * f;
  float s, c;
  sincosf(ang, &s, &c);

  size_t qb = (size_t)tok * 2048 + h * 128 + i;
  float q1 = b2f(Q[qb]), q2 = b2f(Q[qb + 64]);
  Q[qb] = f2b((q1 * c - q2 * s) * scale);
  Q[qb + 64] = f2b((q2 * c + q1 * s) * scale);

  size_t kb = (size_t)tok * 4096 + h * 128 + i;
  float k1 = b2f(KV[kb]), k2 = b2f(KV[kb + 64]);
  KV[kb] = f2b(k1 * c - k2 * s);
  KV[kb + 64] = f2b(k2 * c + k1 * s);
}

// ---------------------------------------------------------------------------
// Flash attention v4 = round-3 kernel body (VGPR 156, no spill) + round-4
// grid (512 blocks, one qt each, big-qt first, 3 blocks/CU co-resident by
// natural limits: LDS 48KB*3 <= 160KB, VGPR 512/156 = 3 waves/SIMD).
// NOTE: launch_bounds kept at (256,1) — the (256,3) cap forced VGPR=84 and
// spilled to scratch (WRITE_SIZE 16->55 MB, round 4 regression).
// ---------------------------------------------------------------------------
__global__ __launch_bounds__(256, 1) void flash_attn(const u16* __restrict__ Q,
                                                     const u16* __restrict__ KV,
                                                     const u16* __restrict__ Vt,
                                                     u16* __restrict__ O) {
  const int S = 2048, D = 2048, KVld = 4096;
  int bh = blockIdx.x;       // 0..31
  int qt = 15 - blockIdx.y;  // 15..0 — long blocks launch first
  int b = bh >> 4, h = bh & 15;
  int tid = threadIdx.x, w = tid >> 6, lane = tid & 63;
  int quad = lane >> 4, l15 = lane & 15;

  const u16* Qb = Q + (size_t)(b * S) * D + h * 128;
  const u16* Kb = KV + (size_t)(b * S) * KVld + h * 128;
  const u16* Vtb = Vt + ((size_t)(b * 2048 + h * 128)) * S;

  __shared__ u16 Ksh[64 * 128];
  __shared__ u16 Vsh[128 * 64];
  __shared__ u16 Psh[4][32 * 64];

  int q0 = qt * 128;
  int qw = q0 + w * 32;

  short8 qf[2][4];
#pragma unroll
  for (int mi = 0; mi < 2; ++mi) {
    const u16* qp = Qb + (size_t)(qw + mi * 16 + l15) * D + quad * 8;
#pragma unroll
    for (int kk = 0; kk < 4; ++kk) qf[mi][kk] = *(const short8*)(qp + kk * 32);
  }

  floatx4 o[2][8];
#pragma unroll
  for (int mi = 0; mi < 2; ++mi)
#pragma unroll
    for (int t = 0; t < 8; ++t) o[mi][t] = floatx4{0.f, 0.f, 0.f, 0.f};
  float mrow[2][4], lrow[2][4];
#pragma unroll
  for (int mi = 0; mi < 2; ++mi)
#pragma unroll
    for (int r = 0; r < 4; ++r) { mrow[mi][r] = -1e30f; lrow[mi][r] = 0.f; }

  int nk = 2 * qt + 2;
  for (int kt = 0; kt < nk; ++kt) {
    int kb = kt * 64;
    __syncthreads();

    // stage K tile [64][128]
#pragma unroll
    for (int tt = 0; tt < 4; ++tt) {
      int r0 = w * 16 + tt * 4;
      int row = r0 + quad;
      int g = (l15 & 8) | ((l15 & 7) ^ (row & 7));
      gl_lds16(Kb + (size_t)(kb + row) * KVld + g * 8, (void*)(Ksh + r0 * 128));
    }
    // stage V^T tile [128][64]
#pragma unroll
    for (int tt = 0; tt < 4; ++tt) {
      int d0 = w * 32 + tt * 8;
      int d = d0 + (lane >> 3);
      int g = (lane & 7) ^ (d & 7);
      gl_lds16(Vtb + (size_t)d * S + kb + g * 8, (void*)(Vsh + d0 * 64));
    }
    __syncthreads();

    if (kb <= qw + 31) {
      // --- QK^T: 2m x 4n x 4ksteps = 32 MFMA ---
      floatx4 sc[2][4];
#pragma unroll
      for (int mi = 0; mi < 2; ++mi)
#pragma unroll
        for (int nf = 0; nf < 4; ++nf) sc[mi][nf] = floatx4{0.f, 0.f, 0.f, 0.f};
#pragma unroll
      for (int kk = 0; kk < 4; ++kk) {
        short8 kf[4];
        int c = kk * 4 + quad;
#pragma unroll
        for (int nf = 0; nf < 4; ++nf) {
          int n = nf * 16 + l15;
          int pc = (c & 8) | ((c & 7) ^ (n & 7));
          kf[nf] = *(const short8*)(Ksh + n * 128 + pc * 8);
        }
#pragma unroll
        for (int mi = 0; mi < 2; ++mi)
#pragma unroll
          for (int nf = 0; nf < 4; ++nf)
            sc[mi][nf] = MFMA16(qf[mi][kk], kf[nf], sc[mi][nf]);
      }

      // --- online softmax (scale pre-folded into Q) ---
      bool masked = (kb + 63 > qw);
#pragma unroll
      for (int mi = 0; mi < 2; ++mi) {
        floatx4 alv;
#pragma unroll
        for (int r = 0; r < 4; ++r) {
          int qg = qw + mi * 16 + quad * 4 + r;
          float v0 = sc[mi][0][r], v1 = sc[mi][1][r];
          float v2 = sc[mi][2][r], v3 = sc[mi][3][r];
          if (masked) {
            v0 = (kb + l15 <= qg) ? v0 : -1e30f;
            v1 = (kb + 16 + l15 <= qg) ? v1 : -1e30f;
            v2 = (kb + 32 + l15 <= qg) ? v2 : -1e30f;
            v3 = (kb + 48 + l15 <= qg) ? v3 : -1e30f;
          }
          float mx = max16(fmaxf(fmaxf(v0, v1), fmaxf(v2, v3)));
          float mn = fmaxf(mrow[mi][r], mx);
          float al = __expf(mrow[mi][r] - mn);
          mrow[mi][r] = mn;
          float p0 = __expf(v0 - mn), p1 = __expf(v1 - mn);
          float p2 = __expf(v2 - mn), p3 = __expf(v3 - mn);
          float rs = sum16((p0 + p1) + (p2 + p3));
          lrow[mi][r] = lrow[mi][r] * al + rs;
          alv[r] = al;
          int m_ = mi * 16 + quad * 4 + r, sw = m_ & 7;
          int cb = l15 >> 3, e = l15 & 7;
          u16* pr = Psh[w] + m_ * 64;
          pr[(((0 + cb) ^ sw) << 3) + e] = f2b(p0);
          pr[(((2 + cb) ^ sw) << 3) + e] = f2b(p1);
          pr[(((4 + cb) ^ sw) << 3) + e] = f2b(p2);
          pr[(((6 + cb) ^ sw) << 3) + e] = f2b(p3);
        }
#pragma unroll
        for (int t = 0; t < 8; ++t) o[mi][t] *= alv;
      }
      __asm__ volatile("s_waitcnt lgkmcnt(0)" ::: "memory");

      // --- PV: 2m x 8d x 2ksteps = 32 MFMA ---
#pragma unroll
      for (int ks = 0; ks < 2; ++ks) {
        int c = ks * 4 + quad;
        short8 pf[2];
#pragma unroll
        for (int mi = 0; mi < 2; ++mi) {
          int m_ = mi * 16 + l15;
          pf[mi] = *(const short8*)(Psh[w] + m_ * 64 + ((c ^ (m_ & 7)) << 3));
        }
#pragma unroll
        for (int t = 0; t < 8; ++t) {
          int d = t * 16 + l15;
          short8 vf = *(const short8*)(Vsh + d * 64 + ((c ^ (d & 7)) << 3));
#pragma unroll
          for (int mi = 0; mi < 2; ++mi) o[mi][t] = MFMA16(pf[mi], vf, o[mi][t]);
        }
      }
    }
  }

  // epilogue
#pragma unroll
  for (int mi = 0; mi < 2; ++mi)
#pragma unroll
    for (int r = 0; r < 4; ++r) {
      float inv = 1.0f / lrow[mi][r];
      int qg = qw + mi * 16 + quad * 4 + r;
      u16* op = O + (size_t)(b * S + qg) * D + h * 128;
#pragma unroll
      for (int t = 0; t < 8; ++t) op[t * 16 + l15] = f2b(o[mi][t][r] * inv);
    }
}

// ---------------------------------------------------------------------------
// Launch. ws (u16 after 64-elem flag pad):
//   xb 8.4M | Wbuf 8.4M (wq -> wkvT -> Vt -> wo) | Qb 8.4M | KVb 16.8M
//   AO aliases xb. Total ~84 MB.
// ---------------------------------------------------------------------------
extern "C" void kernel_launch(void* const* d_in, const int* in_sizes, int n_in,
                              void* d_out, int out_size, void* d_ws, size_t ws_size,
                              hipStream_t stream) {
  const void* x = d_in[0];
  const void* wq = d_in[1];
  const void* wkv = d_in[2];
  const void* wo = d_in[3];

  int* flag = (int*)d_ws;
  u16* xb = (u16*)d_ws + 64;
  u16* Wbuf = xb + (size_t)8388608;
  u16* Qb = Wbuf + (size_t)8388608;
  u16* KVb = Qb + (size_t)8388608;
  u16* AO = xb;  // x dead after KV projection

  detect_f32<<<1, 256, 0, stream>>>((const u16*)x, flag);
  convert_in<<<32768, 256, 0, stream>>>(x, xb, 8388608, flag);
  convert_in<<<16384, 256, 0, stream>>>(wq, Wbuf, 4194304, flag);
  gemm_nt<<<dim3(16, 32), 256, 0, stream>>>(xb, Wbuf, Qb, 4096, 2048, 2048, flag, 0);
  transpose_conv<<<dim3(128, 64), 256, 0, stream>>>(wkv, Wbuf, 2048, 4096, flag);
  gemm_nt<<<dim3(32, 32), 256, 0, stream>>>(xb, Wbuf, KVb, 4096, 4096, 2048, flag, 0);
  transpose_v<<<dim3(64, 64, 2), 256, 0, stream>>>(KVb, Wbuf);  // Wbuf := Vt
  rope_kernel<<<16384, 256, 0, stream>>>(Qb, KVb);
  flash_attn<<<dim3(32, 16), 256, 0, stream>>>(Qb, KVb, Wbuf, AO);
  convert_in<<<16384, 256, 0, stream>>>(wo, Wbuf, 4194304, flag);
  gemm_nt<<<dim3(16, 32), 256, 0, stream>>>(AO, Wbuf, d_out, 4096, 2048, 2048, flag, 1);
}

// Round 6
// 489.558 us; speedup vs baseline: 1.5129x; 1.0669x over previous
//
#include <hip/hip_runtime.h>
#include <stdint.h>

typedef unsigned short u16;
typedef __attribute__((ext_vector_type(8))) short short8;
typedef __attribute__((ext_vector_type(4))) float floatx4;

#define MFMA16(a, b, c) __builtin_amdgcn_mfma_f32_16x16x32_bf16(a, b, c, 0, 0, 0)

static __device__ __forceinline__ void gl_lds16(const void* g, void* l) {
  __builtin_amdgcn_global_load_lds(
      (const __attribute__((address_space(1))) uint32_t*)g,
      (__attribute__((address_space(3))) uint32_t*)l, 16, 0, 0);
}

static __device__ __forceinline__ float b2f(u16 u) {
  union { float f; unsigned u; } v;
  v.u = ((unsigned)u) << 16;
  return v.f;
}
static __device__ __forceinline__ u16 f2b(float f) {
  union { float f; unsigned u; } v;
  v.f = f;
  unsigned r = v.u + 0x7fffu + ((v.u >> 16) & 1u);  // RNE
  return (u16)(r >> 16);
}

// DPP row-rotate reductions over 16-lane groups (VALU, no LDS traffic).
template <int CTRL>
static __device__ __forceinline__ float dppf(float x) {
  return __builtin_bit_cast(
      float, __builtin_amdgcn_update_dpp(0, __builtin_bit_cast(int, x), CTRL,
                                         0xF, 0xF, true));
}
static __device__ __forceinline__ float sum16(float x) {
  x += dppf<0x128>(x);
  x += dppf<0x124>(x);
  x += dppf<0x122>(x);
  x += dppf<0x121>(x);
  return x;
}
static __device__ __forceinline__ float max16(float x) {
  x = fmaxf(x, dppf<0x128>(x));
  x = fmaxf(x, dppf<0x124>(x));
  x = fmaxf(x, dppf<0x122>(x));
  x = fmaxf(x, dppf<0x121>(x));
  return x;
}

// ---------------------------------------------------------------------------
// Input-dtype detector (f32 vs bf16), proven round 2.
// ---------------------------------------------------------------------------
__global__ __launch_bounds__(256) void detect_f32(const u16* __restrict__ x,
                                                  int* __restrict__ flag) {
  __shared__ int cnt[256];
  int c = 0;
  for (int i = threadIdx.x; i < 65536; i += 256) {
    int e = (x[i] >> 7) & 0xFF;
    if (e >= 140) ++c;
  }
  cnt[threadIdx.x] = c;
  __syncthreads();
  for (int s = 128; s > 0; s >>= 1) {
    if (threadIdx.x < (unsigned)s) cnt[threadIdx.x] += cnt[threadIdx.x + s];
    __syncthreads();
  }
  if (threadIdx.x == 0) *flag = (cnt[0] > 1000) ? 1 : 0;
}

// Vectorized flag-aware convert: 8 elems/thread.
__global__ __launch_bounds__(256) void convert_in8(const void* __restrict__ src,
                                                   u16* __restrict__ dst, int n8,
                                                   const int* __restrict__ flag) {
  int i = blockIdx.x * 256 + threadIdx.x;
  if (i >= n8) return;
  short8 r;
  if (*flag) {
    const float4* s = (const float4*)src;
    float4 a = s[2 * i], b = s[2 * i + 1];
    r[0] = (short)f2b(a.x); r[1] = (short)f2b(a.y);
    r[2] = (short)f2b(a.z); r[3] = (short)f2b(a.w);
    r[4] = (short)f2b(b.x); r[5] = (short)f2b(b.y);
    r[6] = (short)f2b(b.z); r[7] = (short)f2b(b.w);
  } else {
    r = ((const short8*)src)[i];
  }
  ((short8*)dst)[i] = r;
}

__global__ __launch_bounds__(256) void transpose_conv(const void* __restrict__ in,
                                                      u16* __restrict__ out,
                                                      int R, int Ccols,
                                                      const int* __restrict__ flag) {
  __shared__ u16 tile[32][33];
  int f = *flag;
  int c0 = blockIdx.x * 32, r0 = blockIdx.y * 32;
  int lx = threadIdx.x & 31, ly = threadIdx.x >> 5;
#pragma unroll
  for (int i = 0; i < 32; i += 8) {
    size_t idx = (size_t)(r0 + ly + i) * Ccols + c0 + lx;
    tile[ly + i][lx] = f ? f2b(((const float*)in)[idx]) : ((const u16*)in)[idx];
  }
  __syncthreads();
#pragma unroll
  for (int i = 0; i < 32; i += 8)
    out[(size_t)(c0 + ly + i) * R + r0 + lx] = tile[lx][ly + i];
}

// V half of KV [4096][4096] -> Vt[b][d][s]  ([2][2048][2048])
__global__ __launch_bounds__(256) void transpose_v(const u16* __restrict__ KV,
                                                   u16* __restrict__ Vt) {
  __shared__ u16 tile[32][33];
  int b = blockIdx.z;
  int d0 = blockIdx.x * 32, s0 = blockIdx.y * 32;
  int lx = threadIdx.x & 31, ly = threadIdx.x >> 5;
  const u16* src = KV + ((size_t)(b * 2048 + s0)) * 4096 + 2048 + d0;
#pragma unroll
  for (int i = 0; i < 32; i += 8)
    tile[ly + i][lx] = src[(size_t)(ly + i) * 4096 + lx];
  __syncthreads();
  u16* dst = Vt + ((size_t)(b * 2048 + d0)) * 2048 + s0;
#pragma unroll
  for (int i = 0; i < 32; i += 8)
    dst[(size_t)(ly + i) * 2048 + lx] = tile[lx][ly + i];
}

// ---------------------------------------------------------------------------
// NT GEMM (m97 structure) — unchanged (passed rounds 2-5).
// ---------------------------------------------------------------------------
__global__ __launch_bounds__(256) void gemm_nt(const u16* __restrict__ A,
                                               const u16* __restrict__ Bm,
                                               void* __restrict__ Cv,
                                               int M, int N, int K,
                                               const int* __restrict__ flag,
                                               int flag_mode) {
  __shared__ u16 Ash[128 * 64];
  __shared__ u16 Bsh[128 * 64];
  int tid = threadIdx.x, w = tid >> 6, lane = tid & 63;
  int quad = lane >> 4, l15 = lane & 15;
  int m0 = blockIdx.y * 128, n0 = blockIdx.x * 128;
  int wm = (w & 1) * 64, wn = (w >> 1) * 64;
  int f32out = flag_mode ? *flag : 0;

  floatx4 acc[4][4];
#pragma unroll
  for (int i = 0; i < 4; ++i)
#pragma unroll
    for (int j = 0; j < 4; ++j) acc[i][j] = floatx4{0.f, 0.f, 0.f, 0.f};

  int srow = lane >> 3;
  int gch = (lane & 7) ^ srow;
  const u16* Ag = A + (size_t)(m0 + w * 32 + srow) * K + gch * 8;
  const u16* Bg = Bm + (size_t)(n0 + w * 32 + srow) * K + gch * 8;

  for (int k0 = 0; k0 < K; k0 += 64) {
    __syncthreads();
#pragma unroll
    for (int t = 0; t < 4; ++t) {
      gl_lds16(Ag + (size_t)t * 8 * K + k0, (void*)(Ash + (w * 32 + t * 8) * 64));
      gl_lds16(Bg + (size_t)t * 8 * K + k0, (void*)(Bsh + (w * 32 + t * 8) * 64));
    }
    __syncthreads();
#pragma unroll
    for (int kk = 0; kk < 2; ++kk) {
      int c = kk * 4 + quad;
      short8 af[4], bf[4];
#pragma unroll
      for (int i = 0; i < 4; ++i) {
        int m = wm + 16 * i + l15;
        af[i] = *(const short8*)(Ash + m * 64 + ((c ^ (m & 7)) << 3));
        int n = wn + 16 * i + l15;
        bf[i] = *(const short8*)(Bsh + n * 64 + ((c ^ (n & 7)) << 3));
      }
#pragma unroll
      for (int i = 0; i < 4; ++i)
#pragma unroll
        for (int j = 0; j < 4; ++j) acc[i][j] = MFMA16(af[i], bf[j], acc[i][j]);
    }
  }

#pragma unroll
  for (int i = 0; i < 4; ++i)
#pragma unroll
    for (int r = 0; r < 4; ++r) {
      int row = m0 + wm + 16 * i + quad * 4 + r;
      if (f32out) {
        float* cp = (float*)Cv + (size_t)row * N + n0 + wn + l15;
#pragma unroll
        for (int j = 0; j < 4; ++j) cp[16 * j] = acc[i][j][r];
      } else {
        u16* cp = (u16*)Cv + (size_t)row * N + n0 + wn + l15;
#pragma unroll
        for (int j = 0; j < 4; ++j) cp[16 * j] = f2b(acc[i][j][r]);
      }
    }
}

// ---------------------------------------------------------------------------
// RoPE in-place; Q additionally scaled by 1/sqrt(dh) (folded from attention).
// ---------------------------------------------------------------------------
__global__ __launch_bounds__(256) void rope_kernel(u16* __restrict__ Q,
                                                   u16* __restrict__ KV) {
  const float scale = 0.08838834764831845f;  // 1/sqrt(128)
  int idx = blockIdx.x * 256 + threadIdx.x;
  int tok = idx >> 10;
  int rem = idx & 1023;
  int h = rem >> 6, i = rem & 63;
  int pos = tok & 2047;
  float f = __powf(10000.0f, -(float)(2 * i) * (1.0f / 128.0f));
  float ang = (float)pos * f;
  float s, c;
  sincosf(ang, &s, &c);

  size_t qb = (size_t)tok * 2048 + h * 128 + i;
  float q1 = b2f(Q[qb]), q2 = b2f(Q[qb + 64]);
  Q[qb] = f2b((q1 * c - q2 * s) * scale);
  Q[qb + 64] = f2b((q2 * c + q1 * s) * scale);

  size_t kb = (size_t)tok * 4096 + h * 128 + i;
  float k1 = b2f(KV[kb]), k2 = b2f(KV[kb + 64]);
  KV[kb] = f2b(k1 * c - k2 * s);
  KV[kb + 64] = f2b(k2 * c + k1 * s);
}

// ---------------------------------------------------------------------------
// Flash attention v5: 512-thread blocks (8 waves x 16 q-rows = 128-row
// q-tile), grid = 32 bh x 8 pairs = 256 EQUAL blocks (pair trick: qt=pair
// then 15-pair -> 34 k-tiles each). 8 waves/CU sustained for the whole
// kernel (round 5's 512x4-wave grid decayed to ~5 waves/CU from imbalance).
// Per-wave state halves vs v4 (1 m-frag: o[8]=32 VGPR) -> no spill at any
// bound; LDS 48KB. Staging via global_load_lds w/ XOR-swizzled global chunk;
// all LDS reads ds_read_b128 at <=2-way bank aliasing.
// ---------------------------------------------------------------------------
__global__ __launch_bounds__(512, 1) void flash_attn(const u16* __restrict__ Q,
                                                     const u16* __restrict__ KV,
                                                     const u16* __restrict__ Vt,
                                                     u16* __restrict__ O) {
  const int S = 2048, D = 2048, KVld = 4096;
  int bh = blockIdx.x;    // 0..31
  int pair = blockIdx.y;  // 0..7
  int b = bh >> 4, h = bh & 15;
  int tid = threadIdx.x, w = tid >> 6, lane = tid & 63;
  int quad = lane >> 4, l15 = lane & 15;

  const u16* Qb = Q + (size_t)(b * S) * D + h * 128;
  const u16* Kb = KV + (size_t)(b * S) * KVld + h * 128;
  const u16* Vtb = Vt + ((size_t)(b * 2048 + h * 128)) * S;

  __shared__ u16 Ksh[64 * 128];    // [krow][d], chunk ^= krow&7
  __shared__ u16 Vsh[128 * 64];    // [d][k],  chunk ^= d&7
  __shared__ u16 Psh[8][16 * 64];  // per-wave P, chunk ^= m&7

  for (int pi = 0; pi < 2; ++pi) {
    int qt = pi ? (15 - pair) : pair;
    int q0 = qt * 128;
    int qw = q0 + w * 16;  // this wave's 16 q-rows

    short8 qf[4];
    {
      const u16* qp = Qb + (size_t)(qw + l15) * D + quad * 8;
#pragma unroll
      for (int kk = 0; kk < 4; ++kk) qf[kk] = *(const short8*)(qp + kk * 32);
    }

    floatx4 o[8];
#pragma unroll
    for (int t = 0; t < 8; ++t) o[t] = floatx4{0.f, 0.f, 0.f, 0.f};
    float mrow[4], lrow[4];
#pragma unroll
    for (int r = 0; r < 4; ++r) { mrow[r] = -1e30f; lrow[r] = 0.f; }

    int nk = 2 * qt + 2;
    for (int kt = 0; kt < nk; ++kt) {
      int kb = kt * 64;
      __syncthreads();

      // stage K tile [64][128]: wave w -> rows [w*8, w*8+8), 2 instrs
#pragma unroll
      for (int tt = 0; tt < 2; ++tt) {
        int r0 = w * 8 + tt * 4;
        int row = r0 + quad;
        int g = (l15 & 8) | ((l15 & 7) ^ (row & 7));
        gl_lds16(Kb + (size_t)(kb + row) * KVld + g * 8, (void*)(Ksh + r0 * 128));
      }
      // stage V^T tile [128][64]: wave w -> d rows [w*16, w*16+16), 2 instrs
#pragma unroll
      for (int tt = 0; tt < 2; ++tt) {
        int d0 = w * 16 + tt * 8;
        int d = d0 + (lane >> 3);
        int g = (lane & 7) ^ (d & 7);
        gl_lds16(Vtb + (size_t)d * S + kb + g * 8, (void*)(Vsh + d0 * 64));
      }
      __syncthreads();

      if (kb <= qw + 15) {  // wave has at least one unmasked row
        // --- QK^T: 4n x 4ksteps = 16 MFMA ---
        floatx4 sc[4];
#pragma unroll
        for (int nf = 0; nf < 4; ++nf) sc[nf] = floatx4{0.f, 0.f, 0.f, 0.f};
#pragma unroll
        for (int kk = 0; kk < 4; ++kk) {
          int c = kk * 4 + quad;
          short8 kf[4];
#pragma unroll
          for (int nf = 0; nf < 4; ++nf) {
            int n = nf * 16 + l15;
            int pc = (c & 8) | ((c & 7) ^ (n & 7));
            kf[nf] = *(const short8*)(Ksh + n * 128 + pc * 8);
          }
#pragma unroll
          for (int nf = 0; nf < 4; ++nf) sc[nf] = MFMA16(qf[kk], kf[nf], sc[nf]);
        }

        // --- online softmax (1/sqrt(dh) pre-folded into Q) ---
        bool masked = (kb + 63 > qw);
        floatx4 alv;
#pragma unroll
        for (int r = 0; r < 4; ++r) {
          int qg = qw + quad * 4 + r;
          float v0 = sc[0][r], v1 = sc[1][r];
          float v2 = sc[2][r], v3 = sc[3][r];
          if (masked) {
            v0 = (kb + l15 <= qg) ? v0 : -1e30f;
            v1 = (kb + 16 + l15 <= qg) ? v1 : -1e30f;
            v2 = (kb + 32 + l15 <= qg) ? v2 : -1e30f;
            v3 = (kb + 48 + l15 <= qg) ? v3 : -1e30f;
          }
          float mx = max16(fmaxf(fmaxf(v0, v1), fmaxf(v2, v3)));
          float mn = fmaxf(mrow[r], mx);
          float al = __expf(mrow[r] - mn);
          mrow[r] = mn;
          float p0 = __expf(v0 - mn), p1 = __expf(v1 - mn);
          float p2 = __expf(v2 - mn), p3 = __expf(v3 - mn);
          float rs = sum16((p0 + p1) + (p2 + p3));
          lrow[r] = lrow[r] * al + rs;
          alv[r] = al;
          int m_ = quad * 4 + r, sw = m_ & 7;
          int cb = l15 >> 3, e = l15 & 7;
          u16* pr = Psh[w] + m_ * 64;
          pr[(((0 + cb) ^ sw) << 3) + e] = f2b(p0);
          pr[(((2 + cb) ^ sw) << 3) + e] = f2b(p1);
          pr[(((4 + cb) ^ sw) << 3) + e] = f2b(p2);
          pr[(((6 + cb) ^ sw) << 3) + e] = f2b(p3);
        }
#pragma unroll
        for (int t = 0; t < 8; ++t) o[t] *= alv;
        __asm__ volatile("s_waitcnt lgkmcnt(0)" ::: "memory");

        // --- PV: 8d x 2ksteps = 16 MFMA ---
#pragma unroll
        for (int ks = 0; ks < 2; ++ks) {
          int c = ks * 4 + quad;
          short8 pf = *(const short8*)(Psh[w] + l15 * 64 + ((c ^ (l15 & 7)) << 3));
#pragma unroll
          for (int t = 0; t < 8; ++t) {
            int d = t * 16 + l15;
            short8 vf = *(const short8*)(Vsh + d * 64 + ((c ^ (d & 7)) << 3));
            o[t] = MFMA16(pf, vf, o[t]);
          }
        }
      }
    }

    // epilogue
#pragma unroll
    for (int r = 0; r < 4; ++r) {
      float inv = 1.0f / lrow[r];
      int qg = qw + quad * 4 + r;
      u16* op = O + (size_t)(b * S + qg) * D + h * 128;
#pragma unroll
      for (int t = 0; t < 8; ++t) op[t * 16 + l15] = f2b(o[t][r] * inv);
    }
  }
}

// ---------------------------------------------------------------------------
// Launch. ws (u16 after 64-elem flag pad):
//   xb 8.4M | Wbuf 8.4M (wq -> wkvT -> Vt -> wo) | Qb 8.4M | KVb 16.8M
//   AO aliases xb. Total ~84 MB.
// ---------------------------------------------------------------------------
extern "C" void kernel_launch(void* const* d_in, const int* in_sizes, int n_in,
                              void* d_out, int out_size, void* d_ws, size_t ws_size,
                              hipStream_t stream) {
  const void* x = d_in[0];
  const void* wq = d_in[1];
  const void* wkv = d_in[2];
  const void* wo = d_in[3];

  int* flag = (int*)d_ws;
  u16* xb = (u16*)d_ws + 64;
  u16* Wbuf = xb + (size_t)8388608;
  u16* Qb = Wbuf + (size_t)8388608;
  u16* KVb = Qb + (size_t)8388608;
  u16* AO = xb;  // x dead after KV projection

  detect_f32<<<1, 256, 0, stream>>>((const u16*)x, flag);
  convert_in8<<<4096, 256, 0, stream>>>(x, xb, 1048576, flag);
  convert_in8<<<2048, 256, 0, stream>>>(wq, Wbuf, 524288, flag);
  gemm_nt<<<dim3(16, 32), 256, 0, stream>>>(xb, Wbuf, Qb, 4096, 2048, 2048, flag, 0);
  transpose_conv<<<dim3(128, 64), 256, 0, stream>>>(wkv, Wbuf, 2048, 4096, flag);
  gemm_nt<<<dim3(32, 32), 256, 0, stream>>>(xb, Wbuf, KVb, 4096, 4096, 2048, flag, 0);
  transpose_v<<<dim3(64, 64, 2), 256, 0, stream>>>(KVb, Wbuf);  // Wbuf := Vt
  rope_kernel<<<16384, 256, 0, stream>>>(Qb, KVb);
  flash_attn<<<dim3(32, 8), 512, 0, stream>>>(Qb, KVb, Wbuf, AO);
  convert_in8<<<2048, 256, 0, stream>>>(wo, Wbuf, 524288, flag);
  gemm_nt<<<dim3(16, 32), 256, 0, stream>>>(AO, Wbuf, d_out, 4096, 2048, 2048, flag, 1);
}